// Round 9
// baseline (124.660 us; speedup 1.0000x reference)
//
#include <hip/hip_runtime.h>
#include <math.h>

#define B 8
#define T 128
#define NKEY 127   // t-1
#define NPAD 128   // padded key count (score row 127 forced to prob 0)
#define KDIM 64    // Q_DIM == KV_DIM
#define NH 4       // heads
#define CH 256     // NH*KDIM output channels

typedef _Float16 half8v __attribute__((ext_vector_type(8)));  // 8 fp16 (4 VGPRs)
typedef float floatx4 __attribute__((ext_vector_type(4)));    // MFMA C/D

// tanh(x) = 1 - 2/(e^{2x}+1). Saturates correctly at +/-inf, no clamp needed.
__device__ __forceinline__ float fast_tanh(float x) {
    float e = __expf(2.f * x);
    float r = __builtin_amdgcn_rcpf(e + 1.f);
    return fmaf(-2.f, r, 1.f);
}

// 8x float -> fp16 RNE. Verified (R15 pass): absmax 4.88e-4.
__device__ __forceinline__ half8v cvt8_rne(const float4& a, const float4& b) {
    half8v h;
    h[0] = (_Float16)a.x; h[1] = (_Float16)a.y;
    h[2] = (_Float16)a.z; h[3] = (_Float16)a.w;
    h[4] = (_Float16)b.x; h[5] = (_Float16)b.y;
    h[6] = (_Float16)b.z; h[7] = (_Float16)b.w;
    return h;
}

// ---- one bt's staging: kv (global) -> fragment-ordered fp16 LDS ----
// chunk = nt*2+ks; write addr = chunk*1024 + lane*16: lane-linear, 0 conflicts.
// Fragment content: kv[nt*16 + (lane&15)][ks*32 + (lane>>4)*8 + j]
__device__ __forceinline__ void stage_kv(_Float16 (*frag)[64][8],
                                         const float* __restrict__ kvg,
                                         int h, int lane) {
    #pragma unroll
    for (int w = 0; w < 4; ++w) {
        const int chunk = w * 4 + h;          // each wave does 4 chunks
        const int nt = chunk >> 1, ks = chunk & 1;
        const int n  = nt * 16 + (lane & 15);
        const int k0 = ks * 32 + (lane >> 4) * 8;
        float4 a = make_float4(0.f, 0.f, 0.f, 0.f);
        float4 b = make_float4(0.f, 0.f, 0.f, 0.f);
        if (n < NKEY) {
            const float* p = kvg + (size_t)n * KDIM + k0;
            a = *(const float4*)p;
            b = *(const float4*)(p + 4);
        }
        *(half8v*)&frag[chunk][lane][0] = cvt8_rne(a, b);
    }
}

// ---- one bt's full compute after its frag/qb are ready: R15 verbatim ----
__device__ __forceinline__ void compute_bt(
    const _Float16 (*frag)[64][8],   // [16][64][8] fp16 B-frags for this bt
    const float* __restrict__ qb,    // [256] query+bias for this bt
    const float* __restrict__ kvg,   // this bt's kv block (Phase B columns)
    const float* __restrict__ Wv,
    float* __restrict__ p_row,       // p_lds[h] (128 floats, wave-private)
    float* __restrict__ wkv_row,     // wkv_lds[h] (64 floats, wave-private)
    const float* __restrict__ wkv_base, // wkv_lds[h] base for Phase C reads
    float* __restrict__ out_bt,      // out + bt*CH
    const half8v ah[4][2],
    const float wsv[4][4],
    int tid, int h, int lane, int quad)
{
    // per-lane qb for epilogue: j = jt*16 + quad*4 + r
    float qbv[4][4];
    #pragma unroll
    for (int jt = 0; jt < 4; ++jt)
        #pragma unroll
        for (int r = 0; r < 4; ++r)
            qbv[jt][r] = qb[h * 64 + jt * 16 + quad * 4 + r];

    // ---- scores: 8 n-tiles of 16 keys; single-pass fp16 MFMA ----
    #pragma unroll
    for (int nt = 0; nt < 8; ++nt) {
        half8v b0 = *(const half8v*)&frag[nt * 2 + 0][lane][0];
        half8v b1 = *(const half8v*)&frag[nt * 2 + 1][lane][0];

        floatx4 acc[4];
        #pragma unroll
        for (int jt = 0; jt < 4; ++jt) {
            floatx4 c = {0.f, 0.f, 0.f, 0.f};
            c = __builtin_amdgcn_mfma_f32_16x16x32_f16(ah[jt][0], b0, c, 0, 0, 0);
            c = __builtin_amdgcn_mfma_f32_16x16x32_f16(ah[jt][1], b1, c, 0, 0, 0);
            acc[jt] = c;
        }

        // epilogue: score[n] = sum_j tanh(key + qb[j]) * ws[j]
        // D layout: col = lane&15 = n in tile, row = quad*4 + r = j in jt
        float partial = 0.f;
        #pragma unroll
        for (int jt = 0; jt < 4; ++jt)
            #pragma unroll
            for (int r = 0; r < 4; ++r)
                partial = fmaf(fast_tanh(acc[jt][r] + qbv[jt][r]), wsv[jt][r], partial);
        partial += __shfl_xor(partial, 16, 64);   // reduce across quads (same col)
        partial += __shfl_xor(partial, 32, 64);
        if (lane < 16) p_row[nt * 16 + lane] = partial;
    }
    // no barrier: wave h is sole writer+reader of p_row (DS in-order)

    // ---- softmax over the 127 real keys (2 scores per lane) ----
    float invl;
    {
        float s_a = p_row[lane];
        float s_b = p_row[64 + lane];
        if (lane == 63) s_b = -1e30f;          // mask pad row 127
        float mx = fmaxf(s_a, s_b);
        #pragma unroll
        for (int off = 32; off > 0; off >>= 1)
            mx = fmaxf(mx, __shfl_xor(mx, off, 64));
        float pa = __expf(s_a - mx);
        float pb = __expf(s_b - mx);           // lane 63 -> 0
        float ls = pa + pb;
        #pragma unroll
        for (int off = 32; off > 0; off >>= 1)
            ls += __shfl_xor(ls, off, 64);
        invl = 1.f / ls;
        p_row[lane]      = pa;                 // unnormalized probs
        p_row[64 + lane] = pb;                 // p_row[127] = 0 masks pad
    }

    // ---- Phase B: wkv[lane] = (sum_n p[n] * kv[n][lane]) / l ----
    {
        const float* kvl = kvg + lane;
        float w0 = 0.f, w1 = 0.f, w2 = 0.f, w3 = 0.f;
        #pragma unroll 8
        for (int n4 = 0; n4 < NPAD; n4 += 4) {
            float4 p4 = *(const float4*)&p_row[n4];          // uniform broadcast
            const int n3 = (n4 + 3 < NKEY) ? (n4 + 3) : 0;   // p4.w==0 there
            w0 = fmaf(p4.x, kvl[(size_t)(n4 + 0) * KDIM], w0);
            w1 = fmaf(p4.y, kvl[(size_t)(n4 + 1) * KDIM], w1);
            w2 = fmaf(p4.z, kvl[(size_t)(n4 + 2) * KDIM], w2);
            w3 = fmaf(p4.w, kvl[(size_t)n3 * KDIM], w3);
        }
        wkv_row[lane] = ((w0 + w1) + (w2 + w3)) * invl;
    }
    // no barrier: wkv_row written and read only by wave h (DS in-order)

    // ---- Phase C: out[j] = wkv[h,:] . Wv[j,:] ----
    {
        const float4* Wv4 = (const float4*)(Wv + (size_t)tid * KDIM);
        const float4* wv_row = (const float4*)wkv_base;
        float4 oa = {0.f, 0.f, 0.f, 0.f};
        #pragma unroll
        for (int i = 0; i < 16; ++i) {
            float4 w = Wv4[i];
            float4 c = wv_row[i];                        // broadcast
            oa.x = fmaf(c.x, w.x, oa.x);
            oa.y = fmaf(c.y, w.y, oa.y);
            oa.z = fmaf(c.z, w.z, oa.z);
            oa.w = fmaf(c.w, w.w, oa.w);
        }
        out_bt[tid] = (oa.x + oa.y) + (oa.z + oa.w);
    }
}

// R16: 2 bt per block, pipelined. R15 counters (42.8us, MfmaUtil 3.6, VALU 29,
// HBM 8%, 70% idle at 4 fully co-resident blocks/CU) say the wall is the
// per-block serial phase chain, not occupancy (R8/R9/R10: 32/41/60% occ, same
// dur). Fix: each block handles bt0,bt1; bt1's kv staging executes right after
// the barrier so its HBM latency + LDS writes land DURING bt0's
// scores/softmax/B/C (~10us of compute); scores1 then starts with zero staging
// wait. Weight sharing comes free: Wq/q read once for both qb's, Wk A-frags
// and ws loaded once. Per-bt compute is the R15-verified code, untouched.
// Grid 512 (2 blocks/CU, LDS 37888 B). (256,2) -> 128 VGPR cap.
__global__ __launch_bounds__(256, 2)
void attn_kernel(const float* __restrict__ q_x,   // (B,T,64)
                 const float* __restrict__ kv_x,  // (B,T,127,64)
                 const float* __restrict__ Wk,    // (256,64)
                 const float* __restrict__ Wq,    // (256,64)
                 const float* __restrict__ Wv,    // (256,64)
                 const float* __restrict__ bias,  // (64,)
                 const float* __restrict__ Ws,    // (1,64)
                 const float* __restrict__ bs,    // (1,) -- cancels in softmax
                 float* __restrict__ out)         // (B,T,256)
{
    __shared__ __align__(16) _Float16 frag[2][16][64][8]; // 32 KB: fp16 B-frags x2
    __shared__ float qb_lds[2][CH];                       // 2 KB: query+bias x2
    __shared__ float p_lds[NH][NPAD];                     // 2 KB (sequentially reused)
    __shared__ __align__(16) float wkv_lds[NH][KDIM];     // 1 KB -> total 37888 B

    const int bt0  = blockIdx.x * 2;
    const int tid  = threadIdx.x;
    const int h    = tid >> 6;    // wave index == head index
    const int lane = tid & 63;
    const int col  = lane & 15;   // MFMA n/m lane index
    const int quad = lane >> 4;   // MFMA k-group / row-group

    const float* __restrict__ kvg0 = kv_x + (size_t)bt0 * NKEY * KDIM;
    const float* __restrict__ kvg1 = kvg0 + (size_t)NKEY * KDIM;

    // ---- stage bt0's kv ----
    stage_kv(frag[0], kvg0, h, lane);

    // ---- qb for BOTH bts in one Wq pass (Wq/bias read once) ----
    {
        const float4* Wq4 = (const float4*)(Wq + (size_t)tid * KDIM);
        const float4* q40 = (const float4*)(q_x + (size_t)bt0 * KDIM);
        const float4* q41 = (const float4*)(q_x + (size_t)(bt0 + 1) * KDIM);
        float4 a0 = {0.f, 0.f, 0.f, 0.f};
        float4 a1 = {0.f, 0.f, 0.f, 0.f};
        #pragma unroll
        for (int i = 0; i < 16; ++i) {
            float4 w  = Wq4[i];
            float4 qa = q40[i];
            float4 qc = q41[i];
            a0.x = fmaf(qa.x, w.x, a0.x);
            a0.y = fmaf(qa.y, w.y, a0.y);
            a0.z = fmaf(qa.z, w.z, a0.z);
            a0.w = fmaf(qa.w, w.w, a0.w);
            a1.x = fmaf(qc.x, w.x, a1.x);
            a1.y = fmaf(qc.y, w.y, a1.y);
            a1.z = fmaf(qc.z, w.z, a1.z);
            a1.w = fmaf(qc.w, w.w, a1.w);
        }
        const float bv = bias[tid & 63];
        qb_lds[0][tid] = (a0.x + a0.y) + (a0.z + a0.w) + bv;
        qb_lds[1][tid] = (a1.x + a1.y) + (a1.z + a1.w) + bv;
    }

    // ---- A-fragments (Wk, bt-independent: loaded ONCE for both bts) ----
    half8v ah[4][2];
    #pragma unroll
    for (int jt = 0; jt < 4; ++jt)
        #pragma unroll
        for (int ks = 0; ks < 2; ++ks) {
            const float* wrow = Wk + (size_t)(h * 64 + jt * 16 + col) * KDIM
                                   + ks * 32 + quad * 8;
            float4 a = *(const float4*)wrow;
            float4 b = *(const float4*)(wrow + 4);
            ah[jt][ks] = cvt8_rne(a, b);
        }

    // ---- ws (bt-independent, loaded once) ----
    float wsv[4][4];
    #pragma unroll
    for (int jt = 0; jt < 4; ++jt)
        #pragma unroll
        for (int r = 0; r < 4; ++r)
            wsv[jt][r] = Ws[jt * 16 + quad * 4 + r];

    __syncthreads();   // B1: frag[0] + qb ready

    // ---- pipelined stage of bt1's kv: HBM latency + LDS writes hide under
    //      the ~10us of bt0 compute below; scores1 then starts stall-free ----
    stage_kv(frag[1], kvg1, h, lane);

    // ---- bt0 full compute (R15-verified code) ----
    compute_bt(frag[0], qb_lds[0], kvg0, Wv,
               p_lds[h], wkv_lds[h], wkv_lds[h],
               out + (size_t)bt0 * CH,
               ah, wsv, tid, h, lane, quad);

    __syncthreads();   // B2: frag[1] writes complete, bt0 done

    // ---- bt1 full compute ----
    compute_bt(frag[1], qb_lds[1], kvg1, Wv,
               p_lds[h], wkv_lds[h], wkv_lds[h],
               out + (size_t)(bt0 + 1) * CH,
               ah, wsv, tid, h, lane, quad);
}

extern "C" void kernel_launch(void* const* d_in, const int* in_sizes, int n_in,
                              void* d_out, int out_size, void* d_ws, size_t ws_size,
                              hipStream_t stream) {
    const float* q_x  = (const float*)d_in[0];
    const float* kv_x = (const float*)d_in[1];
    const float* Wk   = (const float*)d_in[2];
    const float* Wq   = (const float*)d_in[3];
    const float* Wv   = (const float*)d_in[4];
    const float* bias = (const float*)d_in[5];
    const float* Ws   = (const float*)d_in[6];
    const float* bs   = (const float*)d_in[7];
    float* out = (float*)d_out;

    attn_kernel<<<dim3(B * T / 2), dim3(256), 0, stream>>>(
        q_x, kv_x, Wk, Wq, Wv, bias, Ws, bs, out);
}

// Round 10
// 113.498 us; speedup vs baseline: 1.0983x; 1.0983x over previous
//
#include <hip/hip_runtime.h>
#include <math.h>

#define B 8
#define T 128
#define NKEY 127   // t-1
#define NPAD 128   // padded key count (score row 127 forced to prob 0)
#define KDIM 64    // Q_DIM == KV_DIM
#define NH 4       // heads
#define CH 256     // NH*KDIM output channels

typedef _Float16 half8v __attribute__((ext_vector_type(8)));  // 8 fp16 (4 VGPRs)
typedef _Float16 half4v __attribute__((ext_vector_type(4)));  // 4 fp16 (b64)
typedef float floatx4 __attribute__((ext_vector_type(4)));    // MFMA C/D

// tanh(x) = 1 - 2/(e^{2x}+1). Saturates correctly at +/-inf, no clamp needed.
__device__ __forceinline__ float fast_tanh(float x) {
    float e = __expf(2.f * x);
    float r = __builtin_amdgcn_rcpf(e + 1.f);
    return fmaf(-2.f, r, 1.f);
}

// 8x float -> fp16 RNE. Verified (R15 pass): absmax 4.88e-4.
__device__ __forceinline__ half8v cvt8_rne(const float4& a, const float4& b) {
    half8v h;
    h[0] = (_Float16)a.x; h[1] = (_Float16)a.y;
    h[2] = (_Float16)a.z; h[3] = (_Float16)a.w;
    h[4] = (_Float16)b.x; h[5] = (_Float16)b.y;
    h[6] = (_Float16)b.z; h[7] = (_Float16)b.w;
    return h;
}

// R17 = R15 (42.8us, PASSED) + ONE delta: Phase B reads kv from an LDS fp16
// transpose instead of 128 L2-latency global loads per thread.
//   kvT[64][132] fp16, row stride 264 B = 66 dw == 2 (mod 32):
//   - Phase B read: lane k reads its row as 32 linear ds_read_b64; lanes k,k+16
//     alias 2-way (free, m136), k vs k+8 differ by 16 banks -> conflict-free.
//     Plain [k][n] layout, NO swizzle (R11/R13's conflict/indexing traps avoided).
//   - staging write: thread already holds kv[n][k0..k0+7] in registers; 8 extra
//     ds_write_u16; per instr: 4 quads at distinct/2-way banks -> free.
//   - n=127 column: staging writes zeros there (guarded global load), p[127]=0.
// R16's grid restructure reverted (8 waves/CU: 59.5, 16/CU: 42.8, 32/CU: 47.6
// -> R15's 16 waves/CU shape is optimal). Banned trio (C-init qb, floatx4 ws,
// deferred quad-reduce) stays out. LDS 37376 B -> 4 blocks/CU kept.
__global__ __launch_bounds__(256, 2)
void attn_kernel(const float* __restrict__ q_x,   // (B,T,64)
                 const float* __restrict__ kv_x,  // (B,T,127,64)
                 const float* __restrict__ Wk,    // (256,64)
                 const float* __restrict__ Wq,    // (256,64)
                 const float* __restrict__ Wv,    // (256,64)
                 const float* __restrict__ bias,  // (64,)
                 const float* __restrict__ Ws,    // (1,64)
                 const float* __restrict__ bs,    // (1,) -- cancels in softmax
                 float* __restrict__ out)         // (B,T,256)
{
    __shared__ __align__(16) _Float16 frag[16][64][8];   // 16 KB: fp16 B-frags
    __shared__ __align__(16) _Float16 kvT[64][132];      // 16.5 KB: fp16 kv^T
    __shared__ float qb_lds[CH];                         // 1 KB: query+bias
    __shared__ float p_lds[NH][NPAD];                    // 2 KB: scores then probs
    __shared__ __align__(16) float wkv_lds[NH][KDIM];    // 1 KB -> total 37376 B

    const int bt   = blockIdx.x;
    const int tid  = threadIdx.x;
    const int h    = tid >> 6;    // wave index == head index
    const int lane = tid & 63;
    const int col  = lane & 15;   // MFMA n/m lane index
    const int quad = lane >> 4;   // MFMA k-group / row-group

    const float* __restrict__ kvg = kv_x + (size_t)bt * NKEY * KDIM;

    // ---- convert kv (global) -> fragment-ordered fp16 LDS + fp16 kv^T ----
    // chunk = nt*2+ks; frag write addr = chunk*1024 + lane*16: lane-linear.
    // Fragment content: kv[nt*16 + (lane&15)][ks*32 + (lane>>4)*8 + j]
    #pragma unroll
    for (int w = 0; w < 4; ++w) {
        const int chunk = w * 4 + h;          // each wave does 4 chunks
        const int nt = chunk >> 1, ks = chunk & 1;
        const int n  = nt * 16 + (lane & 15);
        const int k0 = ks * 32 + (lane >> 4) * 8;
        float4 a = make_float4(0.f, 0.f, 0.f, 0.f);
        float4 b = make_float4(0.f, 0.f, 0.f, 0.f);
        if (n < NKEY) {
            const float* p = kvg + (size_t)n * KDIM + k0;
            a = *(const float4*)p;
            b = *(const float4*)(p + 4);
        }
        half8v hv = cvt8_rne(a, b);
        *(half8v*)&frag[chunk][lane][0] = hv;
        #pragma unroll
        for (int j = 0; j < 8; ++j)           // transpose: rows k0..k0+7, col n
            kvT[k0 + j][n] = hv[j];           // zeros land in column 127
    }

    // ---- query_j + bias -> qb_lds[channel] ----
    {
        const float4* Wq4 = (const float4*)(Wq + (size_t)tid * KDIM);
        const float4* q4g = (const float4*)(q_x + (size_t)bt * KDIM);
        float4 qa = {0.f, 0.f, 0.f, 0.f};
        #pragma unroll
        for (int i = 0; i < 16; ++i) {
            float4 w = Wq4[i];
            float4 q4 = q4g[i];
            qa.x = fmaf(q4.x, w.x, qa.x);
            qa.y = fmaf(q4.y, w.y, qa.y);
            qa.z = fmaf(q4.z, w.z, qa.z);
            qa.w = fmaf(q4.w, w.w, qa.w);
        }
        qb_lds[tid] = (qa.x + qa.y) + (qa.z + qa.w) + bias[tid & 63];
    }

    // ---- A-fragments: Wk rows of this head, fp16 RNE ----
    // A layout: lane holds Wk[h*64 + jt*16 + col][ks*32 + quad*8 + j]
    half8v ah[4][2];
    #pragma unroll
    for (int jt = 0; jt < 4; ++jt)
        #pragma unroll
        for (int ks = 0; ks < 2; ++ks) {
            const float* wrow = Wk + (size_t)(h * 64 + jt * 16 + col) * KDIM
                                   + ks * 32 + quad * 8;
            float4 a = *(const float4*)wrow;
            float4 b = *(const float4*)(wrow + 4);
            ah[jt][ks] = cvt8_rne(a, b);
        }

    __syncthreads();   // barrier: frags + kvT + qb ready

    // ---- per-lane qb / ws for epilogue: j = jt*16 + quad*4 + r ----
    float qbv[4][4], wsv[4][4];
    #pragma unroll
    for (int jt = 0; jt < 4; ++jt)
        #pragma unroll
        for (int r = 0; r < 4; ++r) {
            int j = jt * 16 + quad * 4 + r;
            qbv[jt][r] = qb_lds[h * 64 + j];
            wsv[jt][r] = Ws[j];
        }

    // ---- scores: 8 n-tiles of 16 keys; single-pass fp16 MFMA ----
    #pragma unroll
    for (int nt = 0; nt < 8; ++nt) {
        half8v b0 = *(const half8v*)&frag[nt * 2 + 0][lane][0];
        half8v b1 = *(const half8v*)&frag[nt * 2 + 1][lane][0];

        floatx4 acc[4];
        #pragma unroll
        for (int jt = 0; jt < 4; ++jt) {
            floatx4 c = {0.f, 0.f, 0.f, 0.f};
            c = __builtin_amdgcn_mfma_f32_16x16x32_f16(ah[jt][0], b0, c, 0, 0, 0);
            c = __builtin_amdgcn_mfma_f32_16x16x32_f16(ah[jt][1], b1, c, 0, 0, 0);
            acc[jt] = c;
        }

        // epilogue: score[n] = sum_j tanh(key + qb[j]) * ws[j]
        // D layout: col = lane&15 = n in tile, row = quad*4 + r = j in jt
        float partial = 0.f;
        #pragma unroll
        for (int jt = 0; jt < 4; ++jt)
            #pragma unroll
            for (int r = 0; r < 4; ++r)
                partial = fmaf(fast_tanh(acc[jt][r] + qbv[jt][r]), wsv[jt][r], partial);
        partial += __shfl_xor(partial, 16, 64);   // reduce across quads (same col)
        partial += __shfl_xor(partial, 32, 64);
        if (lane < 16) p_lds[h][nt * 16 + lane] = partial;
    }
    // no barrier: wave h is sole writer+reader of p_lds[h][*] (DS in-order)

    // ---- softmax over the 127 real keys (2 scores per lane) ----
    float invl;
    {
        float s_a = p_lds[h][lane];
        float s_b = p_lds[h][64 + lane];
        if (lane == 63) s_b = -1e30f;          // mask pad row 127
        float mx = fmaxf(s_a, s_b);
        #pragma unroll
        for (int off = 32; off > 0; off >>= 1)
            mx = fmaxf(mx, __shfl_xor(mx, off, 64));
        float pa = __expf(s_a - mx);
        float pb = __expf(s_b - mx);           // lane 63 -> 0
        float ls = pa + pb;
        #pragma unroll
        for (int off = 32; off > 0; off >>= 1)
            ls += __shfl_xor(ls, off, 64);
        invl = 1.f / ls;
        p_lds[h][lane]      = pa;              // unnormalized probs
        p_lds[h][64 + lane] = pb;              // p_lds[h][127] = 0 masks pad
    }

    // ---- Phase B: wkv[h][k=lane] = (sum_n p[n] * kvT[k][n]) / l, all LDS ----
    // 32 linear ds_read_b64 of row k (266..: stride 264 B == 2 dw mod 32:
    // lanes k,k+16 alias 2-way = free; k,k+8 differ by 16 banks). Probs:
    // float4 uniform broadcast. Column 127 holds zeros; p[127] = 0 too.
    {
        const _Float16* kvr = &kvT[lane][0];
        float w0 = 0.f, w1 = 0.f, w2 = 0.f, w3 = 0.f;
        #pragma unroll 8
        for (int s = 0; s < 32; ++s) {
            half4v v  = *(const half4v*)(kvr + s * 4);
            float4 p4 = *(const float4*)&p_lds[h][s * 4];    // uniform broadcast
            w0 = fmaf(p4.x, (float)v[0], w0);
            w1 = fmaf(p4.y, (float)v[1], w1);
            w2 = fmaf(p4.z, (float)v[2], w2);
            w3 = fmaf(p4.w, (float)v[3], w3);
        }
        wkv_lds[h][lane] = ((w0 + w1) + (w2 + w3)) * invl;
    }
    // no barrier: wkv_lds[h] written and read only by wave h (DS in-order)

    // ---- Phase C: out[j] = wkv[h,:] . Wv[j,:] ----
    {
        const float4* Wv4 = (const float4*)(Wv + (size_t)tid * KDIM);
        const float4* wv_row = (const float4*)wkv_lds[h];
        float4 oa = {0.f, 0.f, 0.f, 0.f};
        #pragma unroll
        for (int i = 0; i < 16; ++i) {
            float4 w = Wv4[i];
            float4 c = wv_row[i];                        // broadcast
            oa.x = fmaf(c.x, w.x, oa.x);
            oa.y = fmaf(c.y, w.y, oa.y);
            oa.z = fmaf(c.z, w.z, oa.z);
            oa.w = fmaf(c.w, w.w, oa.w);
        }
        out[(size_t)bt * CH + tid] = (oa.x + oa.y) + (oa.z + oa.w);
    }
}

extern "C" void kernel_launch(void* const* d_in, const int* in_sizes, int n_in,
                              void* d_out, int out_size, void* d_ws, size_t ws_size,
                              hipStream_t stream) {
    const float* q_x  = (const float*)d_in[0];
    const float* kv_x = (const float*)d_in[1];
    const float* Wk   = (const float*)d_in[2];
    const float* Wq   = (const float*)d_in[3];
    const float* Wv   = (const float*)d_in[4];
    const float* bias = (const float*)d_in[5];
    const float* Ws   = (const float*)d_in[6];
    const float* bs   = (const float*)d_in[7];
    float* out = (float*)d_out;

    attn_kernel<<<dim3(B * T), dim3(256), 0, stream>>>(
        q_x, kv_x, Wk, Wq, Wv, bias, Ws, bs, out);
}